// Round 15
// baseline (96.364 us; speedup 1.0000x reference)
//
#include <hip/hip_runtime.h>

#define NBATCH 16384
#define H 16
#define E 64
#define NB 4                    // batches per wave
#define NBLK (NBATCH / NB)      // 4096 single-wave blocks

typedef __attribute__((ext_vector_type(8))) short short8v;  // 8 bf16 = 4 VGPR
typedef __attribute__((ext_vector_type(4))) float f32x4;

// Compiler-only phase fence (no waitcnt): same-wave DS ops execute in order;
// the compiler inserts fine-grained lgkm waits for register deps. Verified
// correct R10-R14 (absmax 0.0156).
#define CFENCE asm volatile("" ::: "memory")

__device__ __forceinline__ unsigned short f2bf(float x) {
    return (unsigned short)(__float_as_uint(x) >> 16);
}
__device__ __forceinline__ float bfres(float x) {
    return x - __uint_as_float(__float_as_uint(x) & 0xFFFF0000u);
}

// Pure-SSA bf16 hi/lo split of 8 floats (two float4 VALUES) into frags.
#define BSPLIT8(HIv, LOv, A, B) do { \
    HIv[0]=(short)f2bf(A.x); LOv[0]=(short)f2bf(bfres(A.x)); \
    HIv[1]=(short)f2bf(A.y); LOv[1]=(short)f2bf(bfres(A.y)); \
    HIv[2]=(short)f2bf(A.z); LOv[2]=(short)f2bf(bfres(A.z)); \
    HIv[3]=(short)f2bf(A.w); LOv[3]=(short)f2bf(bfres(A.w)); \
    HIv[4]=(short)f2bf(B.x); LOv[4]=(short)f2bf(bfres(B.x)); \
    HIv[5]=(short)f2bf(B.y); LOv[5]=(short)f2bf(bfres(B.y)); \
    HIv[6]=(short)f2bf(B.z); LOv[6]=(short)f2bf(bfres(B.z)); \
    HIv[7]=(short)f2bf(B.w); LOv[7]=(short)f2bf(bfres(B.w)); \
} while (0)

#define FMA4(ACC, S, B) do { \
    ACC.x = fmaf(S, B.x, ACC.x); ACC.y = fmaf(S, B.y, ACC.y); \
    ACC.z = fmaf(S, B.z, ACC.z); ACC.w = fmaf(S, B.w, ACC.w); } while (0)

// 16-lane (xor 1,2,4,8) softmax step for one score value -> normalized prob.
#define SMAX1(X, OUT) do { \
    float mx_ = (X); \
    mx_ = fmaxf(mx_, __shfl_xor(mx_, 1)); \
    mx_ = fmaxf(mx_, __shfl_xor(mx_, 2)); \
    mx_ = fmaxf(mx_, __shfl_xor(mx_, 4)); \
    mx_ = fmaxf(mx_, __shfl_xor(mx_, 8)); \
    float e_ = __expf((X) - mx_); \
    float sm_ = e_; \
    sm_ += __shfl_xor(sm_, 1); \
    sm_ += __shfl_xor(sm_, 2); \
    sm_ += __shfl_xor(sm_, 4); \
    sm_ += __shfl_xor(sm_, 8); \
    OUT = e_ * __builtin_amdgcn_rcpf(sm_); \
} while (0)

// One-time W -> B-frag swizzle (bf16 hi/lo) into global scratch (R13, proven).
// Layout: wsW[((t*2+s)*2 + hl)*512 + L*8 + i], L = col + 16*khi. 16KB; per
// batch it's 16 coalesced 1KB loads -> L1/L2-hot on every CU.
__global__ __launch_bounds__(256) void w_frag_init(
    const float* __restrict__ W, unsigned short* __restrict__ wsW)
{
    const int flat = blockIdx.x * 256 + threadIdx.x;   // 0..4095
    if (flat >= E * E) return;
    const float w = W[flat];
    const int e = flat >> 6, f = flat & 63;
    const int t = f >> 4, col = f & 15;
    const int s = e >> 5, khi = (e >> 3) & 3, i = e & 7;
    const int L = col + 16 * khi;
    wsW[((t * 2 + s) * 2 + 0) * 512 + L * 8 + i] = f2bf(w);
    wsW[((t * 2 + s) * 2 + 1) * 512 + L * 8 + i] = f2bf(bfres(w));
}

// One wave per block, NB batches per wave, full cross-iteration prefetch of
// po AND pm. No block-shared state -> no __syncthreads. LDS 8704B/block ->
// occupancy VGPR-decided (<=128 -> 16 waves/CU; grid 4096 = exactly 16/CU).
// VMEM ordering (in-order retirement!): wsW loads are issued BEFORE the
// next-batch prefetch each iteration, so MFMA's wsW waits never drain the
// prefetch queue. Frag conventions (verified R9-R14):
//   A: lane L holds A[L&15][32s+8*(L>>4)+i]   B: lane L holds B[k][L&15]
//   D: lane L holds D[4*(L>>4)+j][L&15]
// Launch-bounds law (R10-R14): allocator budget = 512/(2*min_waves) ->
// declare (64,1) for a ~256 budget; body needs ~130.
__global__ __launch_bounds__(64, 1) void ovo_kernel(
    const float* __restrict__ o0, const float* __restrict__ o1,
    const float* __restrict__ o2, const float* __restrict__ o3,
    const float* __restrict__ mn, const unsigned short* __restrict__ wsW,
    float* __restrict__ ctx_out, float* __restrict__ attn_out)
{
    __shared__ float sU[H * 68];     // mW (stride 68) -> attnT (16x20) overlay
    __shared__ float sMain[H * 68];  // main rows, stride 68

    const int l = threadIdx.x;
    const int r = l & 15;    // row/col-within-16
    const int q = l >> 4;    // quad selector
    const int bid = blockIdx.x;

    // ---- Prologue: prefetch batch-0 others + main (frag-ordered)
    float4 po0[4], po1[4], po2[4], po3[4];
    float4 pmA, pmB, pmC, pmD;
    {
        const size_t base = (size_t)bid * (H * E);
#pragma unroll
        for (int sc = 0; sc < 4; ++sc) {
            const int s = sc >> 1, c01 = sc & 1;
            const size_t off = base + r * 64 + 32 * s + 8 * q + 4 * c01;
            po0[sc] = *(const float4*)(o0 + off);
            po1[sc] = *(const float4*)(o1 + off);
            po2[sc] = *(const float4*)(o2 + off);
            po3[sc] = *(const float4*)(o3 + off);
        }
        pmA = *(const float4*)(mn + base + r * 64 +      8 * q);
        pmB = *(const float4*)(mn + base + r * 64 +      8 * q + 4);
        pmC = *(const float4*)(mn + base + r * 64 + 32 + 8 * q);
        pmD = *(const float4*)(mn + base + r * 64 + 32 + 8 * q + 4);
    }

#pragma unroll 1
    for (int it = 0; it < NB; ++it) {
        const int batch = it * NBLK + bid;
        const size_t base = (size_t)batch * (H * E);

        // ---- Consume po -> mean -> A-frags (pure SSA; po regs die here)
        short8v ahi[2], alo[2];
#pragma unroll
        for (int s = 0; s < 2; ++s) {
            const int sa = s * 2, sb = s * 2 + 1;
            float4 mA, mB;
            mA.x = ((po0[sa].x + po1[sa].x) + (po2[sa].x + po3[sa].x)) * 0.25f;
            mA.y = ((po0[sa].y + po1[sa].y) + (po2[sa].y + po3[sa].y)) * 0.25f;
            mA.z = ((po0[sa].z + po1[sa].z) + (po2[sa].z + po3[sa].z)) * 0.25f;
            mA.w = ((po0[sa].w + po1[sa].w) + (po2[sa].w + po3[sa].w)) * 0.25f;
            mB.x = ((po0[sb].x + po1[sb].x) + (po2[sb].x + po3[sb].x)) * 0.25f;
            mB.y = ((po0[sb].y + po1[sb].y) + (po2[sb].y + po3[sb].y)) * 0.25f;
            mB.z = ((po0[sb].z + po1[sb].z) + (po2[sb].z + po3[sb].z)) * 0.25f;
            mB.w = ((po0[sb].w + po1[sb].w) + (po2[sb].w + po3[sb].w)) * 0.25f;
            BSPLIT8(ahi[s], alo[s], mA, mB);
        }
        CFENCE;

        // ---- Phase 2: mW = mean @ W. B-frags from global wsW (L1-hot).
        //      These 16 loads are issued BEFORE the next-batch prefetch so
        //      their waits never drain it (in-order vmcnt retirement).
#pragma unroll
        for (int t = 0; t < 4; ++t) {
            short8v bh0 = *(const short8v*)&wsW[((t * 2 + 0) * 2 + 0) * 512 + l * 8];
            short8v bl0 = *(const short8v*)&wsW[((t * 2 + 0) * 2 + 1) * 512 + l * 8];
            short8v bh1 = *(const short8v*)&wsW[((t * 2 + 1) * 2 + 0) * 512 + l * 8];
            short8v bl1 = *(const short8v*)&wsW[((t * 2 + 1) * 2 + 1) * 512 + l * 8];
            f32x4 acc = {0.f, 0.f, 0.f, 0.f};
            acc = __builtin_amdgcn_mfma_f32_16x16x32_bf16(ahi[0], bh0, acc, 0, 0, 0);
            acc = __builtin_amdgcn_mfma_f32_16x16x32_bf16(alo[0], bh0, acc, 0, 0, 0);
            acc = __builtin_amdgcn_mfma_f32_16x16x32_bf16(ahi[0], bl0, acc, 0, 0, 0);
            acc = __builtin_amdgcn_mfma_f32_16x16x32_bf16(ahi[1], bh1, acc, 0, 0, 0);
            acc = __builtin_amdgcn_mfma_f32_16x16x32_bf16(alo[1], bh1, acc, 0, 0, 0);
            acc = __builtin_amdgcn_mfma_f32_16x16x32_bf16(ahi[1], bl1, acc, 0, 0, 0);
#pragma unroll
            for (int j = 0; j < 4; ++j)
                sU[(4 * q + j) * 68 + 16 * t + r] = acc[j];   // 2-way banks
        }

        // ---- Phase 2b: pm -> sMain (frag-position writes; phase 5 reads
        //      rows). pm was prefetched a full iteration ago: zero wait.
        *(float4*)&sMain[r * 68 +      8 * q]     = pmA;
        *(float4*)&sMain[r * 68 +      8 * q + 4] = pmB;
        *(float4*)&sMain[r * 68 + 32 + 8 * q]     = pmC;
        *(float4*)&sMain[r * 68 + 32 + 8 * q + 4] = pmD;
        CFENCE;

        // ---- Phase 3: score = mW @ main^T. A rows from sU (4 b128);
        //      B directly from pm regs (frag-ordered load = B-frag layout).
        f32x4 d3 = {0.f, 0.f, 0.f, 0.f};
        {
            float4 a01 = *(const float4*)&sU[r * 68 + 8 * q];
            float4 a23 = *(const float4*)&sU[r * 68 + 8 * q + 4];
            short8v ah, al2, bh, bl2;
            BSPLIT8(ah, al2, a01, a23);
            BSPLIT8(bh, bl2, pmA, pmB);
            d3 = __builtin_amdgcn_mfma_f32_16x16x32_bf16(ah,  bh,  d3, 0, 0, 0);
            d3 = __builtin_amdgcn_mfma_f32_16x16x32_bf16(al2, bh,  d3, 0, 0, 0);
            d3 = __builtin_amdgcn_mfma_f32_16x16x32_bf16(ah,  bl2, d3, 0, 0, 0);
        }
        {
            float4 a01 = *(const float4*)&sU[r * 68 + 32 + 8 * q];
            float4 a23 = *(const float4*)&sU[r * 68 + 32 + 8 * q + 4];
            short8v ah, al2, bh, bl2;
            BSPLIT8(ah, al2, a01, a23);
            BSPLIT8(bh, bl2, pmC, pmD);
            d3 = __builtin_amdgcn_mfma_f32_16x16x32_bf16(ah,  bh,  d3, 0, 0, 0);
            d3 = __builtin_amdgcn_mfma_f32_16x16x32_bf16(al2, bh,  d3, 0, 0, 0);
            d3 = __builtin_amdgcn_mfma_f32_16x16x32_bf16(ah,  bl2, d3, 0, 0, 0);
        }
        CFENCE;

        // ---- Issue NEXT batch's prefetch (po + pm), AFTER phase 2's wsW
        //      loads; consumed next iteration with a full phase 3-5 + loop
        //      of slack. pm regs are dead here (phase 3 done).
        if (it + 1 < NB) {
            const size_t nbase = base + (size_t)NBLK * (H * E);
#pragma unroll
            for (int sc = 0; sc < 4; ++sc) {
                const int s = sc >> 1, c01 = sc & 1;
                const size_t off = nbase + r * 64 + 32 * s + 8 * q + 4 * c01;
                po0[sc] = *(const float4*)(o0 + off);
                po1[sc] = *(const float4*)(o1 + off);
                po2[sc] = *(const float4*)(o2 + off);
                po3[sc] = *(const float4*)(o3 + off);
            }
            pmA = *(const float4*)(mn + nbase + r * 64 +      8 * q);
            pmB = *(const float4*)(mn + nbase + r * 64 +      8 * q + 4);
            pmC = *(const float4*)(mn + nbase + r * 64 + 32 + 8 * q);
            pmD = *(const float4*)(mn + nbase + r * 64 + 32 + 8 * q + 4);
        }
        CFENCE;

        // ---- Phase 4: softmax on D-layout (lane holds score[4q+j][r])
        float4 at4;
        SMAX1(d3[0], at4.x);
        SMAX1(d3[1], at4.y);
        SMAX1(d3[2], at4.z);
        SMAX1(d3[3], at4.w);
        *(float4*)&sU[r * 20 + 4 * q] = at4;   // attnT[g=r][h=4q+j]
        {   // attn global store: 4 b32, 64B-coalesced per 16-lane group
            float* ap = attn_out + (size_t)batch * (H * H);
            ap[(4 * q + 0) * 16 + r] = at4.x;
            ap[(4 * q + 1) * 16 + r] = at4.y;
            ap[(4 * q + 2) * 16 + r] = at4.z;
            ap[(4 * q + 3) * 16 + r] = at4.w;
        }
        CFENCE;

        // ---- Phase 5: context[h][e] = sum_g attn[h][g]*main[g][e] (pure SSA)
        {
            const int h0 = q * 4, e0c = r * 4;
            float4 c0 = {0.f,0.f,0.f,0.f}, c1 = {0.f,0.f,0.f,0.f};
            float4 c2 = {0.f,0.f,0.f,0.f}, c3 = {0.f,0.f,0.f,0.f};
#pragma unroll
            for (int g = 0; g < 16; ++g) {
                float4 bvv = *(const float4*)&sMain[g * 68 + e0c];
                float4 avv = *(const float4*)&sU[g * 20 + h0];   // attnT
                FMA4(c0, avv.x, bvv);
                FMA4(c1, avv.y, bvv);
                FMA4(c2, avv.z, bvv);
                FMA4(c3, avv.w, bvv);
            }
            float* cp = ctx_out + base;
            *(float4*)(cp + (h0 + 0) * 64 + e0c) = c0;
            *(float4*)(cp + (h0 + 1) * 64 + e0c) = c1;
            *(float4*)(cp + (h0 + 2) * 64 + e0c) = c2;
            *(float4*)(cp + (h0 + 3) * 64 + e0c) = c3;
        }
        CFENCE;   // keep next iter's LDS writes ordered after phase-5 reads
    }
}

extern "C" void kernel_launch(void* const* d_in, const int* in_sizes, int n_in,
                              void* d_out, int out_size, void* d_ws, size_t ws_size,
                              hipStream_t stream) {
    const float* o0 = (const float*)d_in[0];
    const float* o1 = (const float*)d_in[1];
    const float* o2 = (const float*)d_in[2];
    const float* o3 = (const float*)d_in[3];
    const float* mn = (const float*)d_in[4];
    const float* W  = (const float*)d_in[5];
    float* ctx  = (float*)d_out;
    float* attn = ctx + (size_t)NBATCH * H * E;
    unsigned short* wsW = (unsigned short*)d_ws;   // 16KB of scratch

    hipLaunchKernelGGL(w_frag_init, dim3(16), dim3(256), 0, stream, W, wsW);
    hipLaunchKernelGGL(ovo_kernel, dim3(NBLK), dim3(64), 0, stream,
                       o0, o1, o2, o3, mn, wsW, ctx, attn);
}

// Round 16
// 84.599 us; speedup vs baseline: 1.1391x; 1.1391x over previous
//
#include <hip/hip_runtime.h>

#define NBATCH 16384
#define H 16
#define E 64
#define NWAVE 4
#define NGRID 768                 // 3 blocks/CU exactly: 3 x 51.2KB = 153.6 <= 160KB LDS
#define NGROUP (NBATCH / NWAVE)   // 4096 wave-groups, grid-strided

typedef __attribute__((ext_vector_type(8))) short short8v;  // 8 bf16 = 4 VGPR
typedef __attribute__((ext_vector_type(4))) float f32x4;

// Compiler-only phase fence (no waitcnt): same-wave DS ops execute in order;
// the compiler inserts fine-grained lgkm waits for register deps. Verified
// correct R10-R15 (absmax 0.0156).
#define CFENCE asm volatile("" ::: "memory")

__device__ __forceinline__ unsigned short f2bf(float x) {
    return (unsigned short)(__float_as_uint(x) >> 16);
}
__device__ __forceinline__ float bfres(float x) {
    return x - __uint_as_float(__float_as_uint(x) & 0xFFFF0000u);
}

// Pure-SSA bf16 hi/lo split of 8 floats (two float4 VALUES) into frags.
#define BSPLIT8(HIv, LOv, A, B) do { \
    HIv[0]=(short)f2bf(A.x); LOv[0]=(short)f2bf(bfres(A.x)); \
    HIv[1]=(short)f2bf(A.y); LOv[1]=(short)f2bf(bfres(A.y)); \
    HIv[2]=(short)f2bf(A.z); LOv[2]=(short)f2bf(bfres(A.z)); \
    HIv[3]=(short)f2bf(A.w); LOv[3]=(short)f2bf(bfres(A.w)); \
    HIv[4]=(short)f2bf(B.x); LOv[4]=(short)f2bf(bfres(B.x)); \
    HIv[5]=(short)f2bf(B.y); LOv[5]=(short)f2bf(bfres(B.y)); \
    HIv[6]=(short)f2bf(B.z); LOv[6]=(short)f2bf(bfres(B.z)); \
    HIv[7]=(short)f2bf(B.w); LOv[7]=(short)f2bf(bfres(B.w)); \
} while (0)

#define FMA4(ACC, S, B) do { \
    ACC.x = fmaf(S, B.x, ACC.x); ACC.y = fmaf(S, B.y, ACC.y); \
    ACC.z = fmaf(S, B.z, ACC.z); ACC.w = fmaf(S, B.w, ACC.w); } while (0)

// 16-lane (xor 1,2,4,8) softmax step for one score value -> normalized prob.
#define SMAX1(X, OUT) do { \
    float mx_ = (X); \
    mx_ = fmaxf(mx_, __shfl_xor(mx_, 1)); \
    mx_ = fmaxf(mx_, __shfl_xor(mx_, 2)); \
    mx_ = fmaxf(mx_, __shfl_xor(mx_, 4)); \
    mx_ = fmaxf(mx_, __shfl_xor(mx_, 8)); \
    float e_ = __expf((X) - mx_); \
    float sm_ = e_; \
    sm_ += __shfl_xor(sm_, 1); \
    sm_ += __shfl_xor(sm_, 2); \
    sm_ += __shfl_xor(sm_, 4); \
    sm_ += __shfl_xor(sm_, 8); \
    OUT = e_ * __builtin_amdgcn_rcpf(sm_); \
} while (0)

// R14 structure + two fixes:
//  (1) grid 768 = EXACTLY 3 resident blocks/CU (R14's grid 1024 ran 3
//      concurrent + 1 queued -> half the wall at 4 waves/CU; measured
//      occupancy 18% vs 37.5% cap). Grid-stride over 4096 wave-groups;
//      blocks 0-255 do 6 iters, 256-767 do 5; each CU gets one 6-iter
//      block (bid%8 XCD spread) -> balanced.
//  (2) pm (main) joins the cross-iteration prefetch (R15-proven frag-
//      ordered load doubles as phase-3 B-operand), removing the ~500cy
//      same-iteration pm wait in phase 2b. pm_next is issued after
//      phase 3 where old pm dies (in-order vmcnt stays safe).
// Frag conventions (verified R9-R15):
//   A: lane L holds A[L&15][32s+8*(L>>4)+i]   B: lane L holds B[k][L&15]
//   D: lane L holds D[4*(L>>4)+j][L&15]
// Launch-bounds law (R10-R14): allocator budget = 512/(2*min_waves);
// declare (256,1) -> ~256 budget; body needs ~130; 12 waves/CU needs <=170.
__global__ __launch_bounds__(256, 1) void ovo_kernel(
    const float* __restrict__ o0, const float* __restrict__ o1,
    const float* __restrict__ o2, const float* __restrict__ o3,
    const float* __restrict__ mn, const float* __restrict__ W,
    float* __restrict__ ctx_out, float* __restrict__ attn_out)
{
    __shared__ __align__(16) unsigned short sWfrag[4][2][2][512];  // 16KB
    __shared__ float sT[NWAVE][2][H * 68];   // per-wave: [0]=sU, [1]=sMain

    const int tid = threadIdx.x;
    const int l   = tid & 63;
    const int wv  = tid >> 6;
    const int r   = l & 15;    // row/col-within-16
    const int q   = l >> 4;    // quad selector
    const int bid = blockIdx.x;

    // ---- One-time: W -> B-frag order, bf16 split (verified R9-R14)
    for (int rr = 0; rr < 16; ++rr) {
        const int flat = rr * 256 + tid;
        const float w = W[flat];
        const int e = flat >> 6, f = flat & 63;
        const int t = f >> 4, col = f & 15;
        const int s = e >> 5, khi = (e >> 3) & 3, i = e & 7;
        const int L = col + 16 * khi;
        sWfrag[t][s][0][L * 8 + i] = f2bf(w);
        sWfrag[t][s][1][L * 8 + i] = f2bf(bfres(w));
    }

    // ---- Prologue: prefetch group bid's others + main (frag-ordered)
    float4 po0[4], po1[4], po2[4], po3[4];
    float4 pmA, pmB, pmC, pmD;
    {
        const size_t base = (size_t)(bid * NWAVE + wv) * (H * E);
#pragma unroll
        for (int sc = 0; sc < 4; ++sc) {
            const int s = sc >> 1, c01 = sc & 1;
            const size_t off = base + r * 64 + 32 * s + 8 * q + 4 * c01;
            po0[sc] = *(const float4*)(o0 + off);
            po1[sc] = *(const float4*)(o1 + off);
            po2[sc] = *(const float4*)(o2 + off);
            po3[sc] = *(const float4*)(o3 + off);
        }
        pmA = *(const float4*)(mn + base + r * 64 +      8 * q);
        pmB = *(const float4*)(mn + base + r * 64 +      8 * q + 4);
        pmC = *(const float4*)(mn + base + r * 64 + 32 + 8 * q);
        pmD = *(const float4*)(mn + base + r * 64 + 32 + 8 * q + 4);
    }
    __syncthreads();   // sWfrag ready; once per block

    float* const sU    = &sT[wv][0][0];   // mW (stride 68) -> attnT (16x20)
    float* const sMain = &sT[wv][1][0];   // main rows, stride 68

#pragma unroll 1
    for (int g = bid; g < NGROUP; g += NGRID) {
        const int batch = g * NWAVE + wv;
        const size_t base = (size_t)batch * (H * E);
        const size_t nbase = (size_t)((g + NGRID) * NWAVE + wv) * (H * E);
        const bool more = (g + NGRID) < NGROUP;

        // ---- Consume po -> mean -> A-frags (pure SSA; po regs die here).
        //      po was issued a full iteration ago: wait ~0.
        short8v ahi[2], alo[2];
#pragma unroll
        for (int s = 0; s < 2; ++s) {
            const int sa = s * 2, sb = s * 2 + 1;
            float4 mA, mB;
            mA.x = ((po0[sa].x + po1[sa].x) + (po2[sa].x + po3[sa].x)) * 0.25f;
            mA.y = ((po0[sa].y + po1[sa].y) + (po2[sa].y + po3[sa].y)) * 0.25f;
            mA.z = ((po0[sa].z + po1[sa].z) + (po2[sa].z + po3[sa].z)) * 0.25f;
            mA.w = ((po0[sa].w + po1[sa].w) + (po2[sa].w + po3[sa].w)) * 0.25f;
            mB.x = ((po0[sb].x + po1[sb].x) + (po2[sb].x + po3[sb].x)) * 0.25f;
            mB.y = ((po0[sb].y + po1[sb].y) + (po2[sb].y + po3[sb].y)) * 0.25f;
            mB.z = ((po0[sb].z + po1[sb].z) + (po2[sb].z + po3[sb].z)) * 0.25f;
            mB.w = ((po0[sb].w + po1[sb].w) + (po2[sb].w + po3[sb].w)) * 0.25f;
            BSPLIT8(ahi[s], alo[s], mA, mB);
        }

        // ---- Issue NEXT group's others now (max slack: consumed next iter)
        if (more) {
#pragma unroll
            for (int sc = 0; sc < 4; ++sc) {
                const int s = sc >> 1, c01 = sc & 1;
                const size_t off = nbase + r * 64 + 32 * s + 8 * q + 4 * c01;
                po0[sc] = *(const float4*)(o0 + off);
                po1[sc] = *(const float4*)(o1 + off);
                po2[sc] = *(const float4*)(o2 + off);
                po3[sc] = *(const float4*)(o3 + off);
            }
        }
        CFENCE;

        // ---- Phase 2: mW = mean @ W (LDS B-frags, conflict-free b128)
#pragma unroll
        for (int t = 0; t < 4; ++t) {
            short8v bh0 = *(const short8v*)&sWfrag[t][0][0][l * 8];
            short8v bl0 = *(const short8v*)&sWfrag[t][0][1][l * 8];
            short8v bh1 = *(const short8v*)&sWfrag[t][1][0][l * 8];
            short8v bl1 = *(const short8v*)&sWfrag[t][1][1][l * 8];
            f32x4 acc = {0.f, 0.f, 0.f, 0.f};
            acc = __builtin_amdgcn_mfma_f32_16x16x32_bf16(ahi[0], bh0, acc, 0, 0, 0);
            acc = __builtin_amdgcn_mfma_f32_16x16x32_bf16(alo[0], bh0, acc, 0, 0, 0);
            acc = __builtin_amdgcn_mfma_f32_16x16x32_bf16(ahi[0], bl0, acc, 0, 0, 0);
            acc = __builtin_amdgcn_mfma_f32_16x16x32_bf16(ahi[1], bh1, acc, 0, 0, 0);
            acc = __builtin_amdgcn_mfma_f32_16x16x32_bf16(alo[1], bh1, acc, 0, 0, 0);
            acc = __builtin_amdgcn_mfma_f32_16x16x32_bf16(ahi[1], bl1, acc, 0, 0, 0);
#pragma unroll
            for (int j = 0; j < 4; ++j)
                sU[(4 * q + j) * 68 + 16 * t + r] = acc[j];   // 2-way banks
        }

        // ---- Phase 2b: pm -> sMain (frag-position writes, 2-way banks;
        //      pm prefetched a full iteration ago: zero wait)
        *(float4*)&sMain[r * 68 +      8 * q]     = pmA;
        *(float4*)&sMain[r * 68 +      8 * q + 4] = pmB;
        *(float4*)&sMain[r * 68 + 32 + 8 * q]     = pmC;
        *(float4*)&sMain[r * 68 + 32 + 8 * q + 4] = pmD;
        CFENCE;

        // ---- Phase 3: score = mW @ main^T. A rows from sU (4 b128);
        //      B directly from pm regs (frag-ordered load = B-frag layout).
        f32x4 d3 = {0.f, 0.f, 0.f, 0.f};
        {
            float4 a01 = *(const float4*)&sU[r * 68 + 8 * q];
            float4 a23 = *(const float4*)&sU[r * 68 + 8 * q + 4];
            short8v ah, al2, bh, bl2;
            BSPLIT8(ah, al2, a01, a23);
            BSPLIT8(bh, bl2, pmA, pmB);
            d3 = __builtin_amdgcn_mfma_f32_16x16x32_bf16(ah,  bh,  d3, 0, 0, 0);
            d3 = __builtin_amdgcn_mfma_f32_16x16x32_bf16(al2, bh,  d3, 0, 0, 0);
            d3 = __builtin_amdgcn_mfma_f32_16x16x32_bf16(ah,  bl2, d3, 0, 0, 0);
        }
        {
            float4 a01 = *(const float4*)&sU[r * 68 + 32 + 8 * q];
            float4 a23 = *(const float4*)&sU[r * 68 + 32 + 8 * q + 4];
            short8v ah, al2, bh, bl2;
            BSPLIT8(ah, al2, a01, a23);
            BSPLIT8(bh, bl2, pmC, pmD);
            d3 = __builtin_amdgcn_mfma_f32_16x16x32_bf16(ah,  bh,  d3, 0, 0, 0);
            d3 = __builtin_amdgcn_mfma_f32_16x16x32_bf16(al2, bh,  d3, 0, 0, 0);
            d3 = __builtin_amdgcn_mfma_f32_16x16x32_bf16(ah,  bl2, d3, 0, 0, 0);
        }
        CFENCE;

        // ---- Issue NEXT group's main (old pm died in phase 3)
        if (more) {
            pmA = *(const float4*)(mn + nbase + r * 64 +      8 * q);
            pmB = *(const float4*)(mn + nbase + r * 64 +      8 * q + 4);
            pmC = *(const float4*)(mn + nbase + r * 64 + 32 + 8 * q);
            pmD = *(const float4*)(mn + nbase + r * 64 + 32 + 8 * q + 4);
        }
        CFENCE;

        // ---- Phase 4: softmax on D-layout (lane holds score[4q+j][r])
        float4 at4;
        SMAX1(d3[0], at4.x);
        SMAX1(d3[1], at4.y);
        SMAX1(d3[2], at4.z);
        SMAX1(d3[3], at4.w);
        *(float4*)&sU[r * 20 + 4 * q] = at4;   // attnT[g=r][h=4q+j]
        {   // attn global store: 4 b32, 64B-coalesced per 16-lane group
            float* ap = attn_out + (size_t)batch * (H * H);
            ap[(4 * q + 0) * 16 + r] = at4.x;
            ap[(4 * q + 1) * 16 + r] = at4.y;
            ap[(4 * q + 2) * 16 + r] = at4.z;
            ap[(4 * q + 3) * 16 + r] = at4.w;
        }
        CFENCE;

        // ---- Phase 5: context[h][e] = sum_g attn[h][g]*main[g][e] (pure SSA)
        {
            const int h0 = q * 4, e0c = r * 4;
            float4 c0 = {0.f,0.f,0.f,0.f}, c1 = {0.f,0.f,0.f,0.f};
            float4 c2 = {0.f,0.f,0.f,0.f}, c3 = {0.f,0.f,0.f,0.f};
#pragma unroll
            for (int gg = 0; gg < 16; ++gg) {
                float4 bvv = *(const float4*)&sMain[gg * 68 + e0c];
                float4 avv = *(const float4*)&sU[gg * 20 + h0];   // attnT
                FMA4(c0, avv.x, bvv);
                FMA4(c1, avv.y, bvv);
                FMA4(c2, avv.z, bvv);
                FMA4(c3, avv.w, bvv);
            }
            float* cp = ctx_out + base;
            *(float4*)(cp + (h0 + 0) * 64 + e0c) = c0;
            *(float4*)(cp + (h0 + 1) * 64 + e0c) = c1;
            *(float4*)(cp + (h0 + 2) * 64 + e0c) = c2;
            *(float4*)(cp + (h0 + 3) * 64 + e0c) = c3;
        }
        CFENCE;   // keep next iter's LDS writes ordered after phase-5 reads
    }
}

extern "C" void kernel_launch(void* const* d_in, const int* in_sizes, int n_in,
                              void* d_out, int out_size, void* d_ws, size_t ws_size,
                              hipStream_t stream) {
    const float* o0 = (const float*)d_in[0];
    const float* o1 = (const float*)d_in[1];
    const float* o2 = (const float*)d_in[2];
    const float* o3 = (const float*)d_in[3];
    const float* mn = (const float*)d_in[4];
    const float* W  = (const float*)d_in[5];
    float* ctx  = (float*)d_out;
    float* attn = ctx + (size_t)NBATCH * H * E;
    hipLaunchKernelGGL(ovo_kernel, dim3(NGRID), dim3(NWAVE * 64), 0, stream,
                       o0, o1, o2, o3, mn, W, ctx, attn);
}